// Round 8
// baseline (1605.044 us; speedup 1.0000x reference)
//
#include <hip/hip_runtime.h>
#include <hip/hip_bf16.h>

typedef __attribute__((ext_vector_type(8))) short short8;
typedef __attribute__((ext_vector_type(4))) float f32x4;
typedef unsigned short ushort;
typedef unsigned long long u64;
typedef unsigned int u32;

#define GBLK 64   // 8 groups x 8 blocks; trivially co-resident on 256 CUs
#define NLOC 6    // optimistic local-channel poll rounds before LLC fallback

__device__ inline ushort f2bf(float x) {
  __hip_bfloat16 h = __float2bfloat16(x);
  return *reinterpret_cast<ushort*>(&h);
}
__device__ inline float bfhi2f(u32 lo) {
  union { u32 u; float f; } c; c.u = lo & 0xFFFF0000u; return c.f;
}
__device__ inline float bflo2f(u32 lo) {
  union { u32 u; float f; } c; c.u = lo << 16; return c.f;
}

// sc0 (L1-bypass, XCD-L2-coherent) 8B store: dirty line stays in own XCD L2.
__device__ inline void store8_sc0(u64* p, u64 v) {
  asm volatile("global_store_dwordx2 %0, %1, off sc0" :: "v"(p), "v"(v) : "memory");
}
// batched 6x sc0 loads + single waitcnt; early-clobber outputs so async-written
// dests can never alias a later load's address pair.
__device__ inline void poll6_sc0(const u64* p0, const u64* p1, const u64* p2,
                                 const u64* p3, const u64* p4, const u64* p5,
                                 u64& x0, u64& x1, u64& x2, u64& x3, u64& x4, u64& x5) {
  asm volatile(
      "global_load_dwordx2 %0, %6, off sc0\n\t"
      "global_load_dwordx2 %1, %7, off sc0\n\t"
      "global_load_dwordx2 %2, %8, off sc0\n\t"
      "global_load_dwordx2 %3, %9, off sc0\n\t"
      "global_load_dwordx2 %4, %10, off sc0\n\t"
      "global_load_dwordx2 %5, %11, off sc0\n\t"
      "s_waitcnt vmcnt(0)"
      : "=&v"(x0), "=&v"(x1), "=&v"(x2), "=&v"(x3), "=&v"(x4), "=&v"(x5)
      : "v"(p0), "v"(p1), "v"(p2), "v"(p3), "v"(p4), "v"(p5)
      : "memory");
}

// ---------------- merged casts f32 -> bf16 ----------------
__global__ void cast2_kernel(const float* __restrict__ a, ushort* __restrict__ oa, int na,
                             const float* __restrict__ b, ushort* __restrict__ ob, int nb) {
  int i = blockIdx.x * blockDim.x + threadIdx.x;
  int st = gridDim.x * blockDim.x;
  for (; i < na + nb; i += st) {
    if (i < na) oa[i] = f2bf(a[i]);
    else        ob[i - na] = f2bf(b[i - na]);
  }
}

// ---------------- 3 residual MLPs in one dispatch (blockIdx.y selects) ----------------
__global__ __launch_bounds__(256) void mlp3_kernel(
    const float* X0, const float* W10, const float* b10, const float* W20, const float* b20,
    const float* g0, const float* be0, float* of0, ushort* ob0,
    const float* X1, const float* W11, const float* b11, const float* W21, const float* b21,
    const float* g1, const float* be1, float* of1, ushort* ob1,
    const float* X2, const float* W12, const float* b12, const float* W22, const float* b22,
    const float* g2, const float* be2, float* of2, ushort* ob2)
{
  const float *X, *W1, *b1, *W2, *b2, *g, *beta; float* of32; ushort* obf;
  int y = blockIdx.y;
  if (y == 0)      { X=X0; W1=W10; b1=b10; W2=W20; b2=b20; g=g0; beta=be0; of32=of0; obf=ob0; }
  else if (y == 1) { X=X1; W1=W11; b1=b11; W2=W21; b2=b21; g=g1; beta=be1; of32=of1; obf=ob1; }
  else             { X=X2; W1=W12; b1=b12; W2=W22; b2=b22; g=g2; beta=be2; of32=of2; obf=ob2; }

  __shared__ float Xs[16 * 260];
  __shared__ float H1s[16 * 260];
  __shared__ float mu_s[16], rs_s[16];
  int tid = threadIdx.x;
  int r0 = blockIdx.x * 16;
  for (int q = 0; q < 16; ++q) Xs[q * 260 + tid] = X[(r0 + q) * 256 + tid];
  __syncthreads();
  int r = tid & 15, jg = tid >> 4;
  for (int jj = 0; jj < 16; ++jj) {
    int j = jg * 16 + jj;
    const float4* wrow = (const float4*)(W1 + j * 256);
    const float4* xrow = (const float4*)(Xs + r * 260);
    float acc = 0.f;
#pragma unroll 8
    for (int kq = 0; kq < 64; ++kq) {
      float4 w = wrow[kq], x = xrow[kq];
      acc += w.x * x.x + w.y * x.y + w.z * x.z + w.w * x.w;
    }
    acc += b1[j];
    H1s[r * 260 + j] = acc > 0.f ? acc : 0.f;
  }
  __syncthreads();
  for (int jj = 0; jj < 16; ++jj) {
    int j = jg * 16 + jj;
    const float4* wrow = (const float4*)(W2 + j * 256);
    const float4* hrow = (const float4*)(H1s + r * 260);
    float acc = 0.f;
#pragma unroll 8
    for (int kq = 0; kq < 64; ++kq) {
      float4 w = wrow[kq], x = hrow[kq];
      acc += w.x * x.x + w.y * x.y + w.z * x.z + w.w * x.w;
    }
    acc += b2[j];
    float v = (acc > 0.f ? acc : 0.f) + H1s[r * 260 + j];
    Xs[r * 260 + j] = v;
  }
  __syncthreads();
  if (tid < 16) {
    float s = 0.f, s2 = 0.f;
    for (int k = 0; k < 256; ++k) { float x = Xs[tid * 260 + k]; s += x; s2 += x * x; }
    float mu = s * (1.0f / 256.0f);
    float var = s2 * (1.0f / 256.0f) - mu * mu;
    mu_s[tid] = mu; rs_s[tid] = rsqrtf(var + 1e-5f);
  }
  __syncthreads();
  for (int q = 0; q < 16; ++q) {
    float x = (Xs[q * 260 + tid] - mu_s[q]) * rs_s[q] * g[tid] + beta[tid];
    if (of32) of32[(r0 + q) * 256 + tid] = x;
    if (obf)  obf[(r0 + q) * 256 + tid] = f2bf(x);
  }
}

// ---------------- start head ----------------
__global__ __launch_bounds__(1024) void shead_kernel(
    const float* __restrict__ h, const float* __restrict__ Wo, const float* __restrict__ bo,
    float* __restrict__ start)
{
  __shared__ float red[16];
  __shared__ float lse_s;
  int tid = threadIdx.x;
  const float4* wr = (const float4*)Wo;
  const float4* hr = (const float4*)(h + tid * 256);
  float acc = 0.f;
  for (int kq = 0; kq < 64; ++kq) {
    float4 w = wr[kq], x = hr[kq];
    acc += w.x * x.x + w.y * x.y + w.z * x.z + w.w * x.w;
  }
  acc += bo[0];
  float s = __expf(acc);
  for (int m = 1; m < 64; m <<= 1) s += __shfl_xor(s, m);
  if ((tid & 63) == 0) red[tid >> 6] = s;
  __syncthreads();
  if (tid == 0) {
    float t = 0.f;
    for (int w = 0; w < 16; ++w) t += red[w];
    lse_s = logf(t);
  }
  __syncthreads();
  start[tid] = acc - lse_s;
}

// ---------------- bf16 MFMA GEMM, tile 64x32, K=256, D = A @ B^T ----------------
__global__ __launch_bounds__(256) void gemm_kernel(
    const ushort* __restrict__ A, const ushort* __restrict__ Bw,
    int mode, int Nvalid,
    const float* __restrict__ bias,
    float* __restrict__ out, float* __restrict__ esum, const int* __restrict__ text)
{
  __shared__ ushort As[64 * 264];
  __shared__ ushort Bs[32 * 264];
  int tid = threadIdx.x;
  int m0 = blockIdx.x * 64, n0 = blockIdx.y * 32;
#pragma unroll
  for (int q = 0; q < 8; ++q) {
    int idx = q * 256 + tid;
    int row = idx >> 5, c8 = idx & 31;
    *(short8*)(As + row * 264 + c8 * 8) = *(const short8*)(A + (m0 + row) * 256 + c8 * 8);
  }
#pragma unroll
  for (int q = 0; q < 4; ++q) {
    int idx = q * 256 + tid;
    int row = idx >> 5, c8 = idx & 31;
    int grow = n0 + row;
    short8 val = {0, 0, 0, 0, 0, 0, 0, 0};
    if (mode == 2) {
      int v = text[(grow & 15) * 256 + (grow >> 4)];
      val = *(const short8*)(Bw + v * 256 + c8 * 8);
    } else if (grow < Nvalid) {
      val = *(const short8*)(Bw + grow * 256 + c8 * 8);
    }
    *(short8*)(Bs + row * 264 + c8 * 8) = val;
  }
  __syncthreads();
  int lane = tid & 63, wave = tid >> 6;
  int r16 = lane & 15, quad = lane >> 4;
  f32x4 acc0 = {0.f, 0.f, 0.f, 0.f}, acc1 = {0.f, 0.f, 0.f, 0.f};
#pragma unroll
  for (int kb = 0; kb < 8; ++kb) {
    short8 a  = *(const short8*)(As + (wave * 16 + r16) * 264 + kb * 32 + quad * 8);
    short8 b0 = *(const short8*)(Bs + r16 * 264 + kb * 32 + quad * 8);
    short8 b1 = *(const short8*)(Bs + (16 + r16) * 264 + kb * 32 + quad * 8);
    acc0 = __builtin_amdgcn_mfma_f32_16x16x32_bf16(a, b0, acc0, 0, 0, 0);
    acc1 = __builtin_amdgcn_mfma_f32_16x16x32_bf16(a, b1, acc1, 0, 0, 0);
  }
  if (mode == 0) {
#pragma unroll
    for (int rr = 0; rr < 4; ++rr) {
      int row = m0 + wave * 16 + quad * 4 + rr;
      int c0 = n0 + r16, c1 = n0 + 16 + r16;
      out[row * 1024 + c0] = acc0[rr] + bias[c0];
      out[row * 1024 + c1] = acc1[rr] + bias[c1];
    }
  } else if (mode == 1) {
    float sums[4];
#pragma unroll
    for (int rr = 0; rr < 4; ++rr) {
      int c0 = n0 + r16, c1 = n0 + 16 + r16;
      float p0 = (c0 < Nvalid) ? __expf(acc0[rr] + bias[c0]) : 0.f;
      float p1 = (c1 < Nvalid) ? __expf(acc1[rr] + bias[c1]) : 0.f;
      float s = p0 + p1;
      s += __shfl_xor(s, 1); s += __shfl_xor(s, 2);
      s += __shfl_xor(s, 4); s += __shfl_xor(s, 8);
      sums[rr] = s;
    }
    if (r16 == 0) {
#pragma unroll
      for (int rr = 0; rr < 4; ++rr)
        atomicAdd(esum + m0 + wave * 16 + quad * 4 + rr, sums[rr]);
    }
  } else {
    int c0 = m0 + wave * 16 + quad * 4;
    int tb0 = n0 + r16, tb1 = n0 + 16 + r16;
    int v0 = text[(tb0 & 15) * 256 + (tb0 >> 4)];
    int v1 = text[(tb1 & 15) * 256 + (tb1 >> 4)];
    float l0 = logf(esum[c0]), l1 = logf(esum[c0 + 1]);
    float l2 = logf(esum[c0 + 2]), l3 = logf(esum[c0 + 3]);
    float4 o0, o1;
    o0.x = acc0[0] + bias[v0] - l0; o0.y = acc0[1] + bias[v0] - l1;
    o0.z = acc0[2] + bias[v0] - l2; o0.w = acc0[3] + bias[v0] - l3;
    o1.x = acc1[0] + bias[v1] - l0; o1.y = acc1[1] + bias[v1] - l1;
    o1.z = acc1[2] + bias[v1] - l2; o1.w = acc1[3] + bias[v1] - l3;
    *(float4*)(out + tb0 * 1024 + c0) = o0;
    *(float4*)(out + tb1 * 1024 + c0) = o1;
  }
}

// ---------------- transition: per-row log_softmax, scatter exp(T) in B-fragment order ----------------
__global__ __launch_bounds__(256) void trans_kernel(
    const float* __restrict__ logits, ushort* __restrict__ texp_frag)
{
  __shared__ float red[4];
  __shared__ float lse_s;
  int i = blockIdx.x, tid = threadIdx.x;
  float x[4];
  float s = 0.f;
#pragma unroll
  for (int q = 0; q < 4; ++q) { x[q] = logits[i * 1024 + q * 256 + tid]; s += __expf(x[q]); }
  for (int m = 1; m < 64; m <<= 1) s += __shfl_xor(s, m);
  if ((tid & 63) == 0) red[tid >> 6] = s;
  __syncthreads();
  if (tid == 0) lse_s = logf(red[0] + red[1] + red[2] + red[3]);
  __syncthreads();
  float lse = lse_s;
  int kblk = i >> 5, quad = (i >> 3) & 3, idx = i & 7;
#pragma unroll
  for (int q = 0; q < 4; ++q) {
    int j = q * 256 + tid;
    int pos = (((j >> 4) * 32 + kblk) * 64 + quad * 16 + (j & 15)) * 8 + idx;
    texp_frag[pos] = f2bf(__expf(x[q] - lse));
  }
}

// ---------------- persistent forward scan: 8 groups x 8 blocks ----------------
// Group g = p&7 owns batches {2g, 2g+1}; block pg = p>>3 owns cols [128pg, 128pg+128).
// Exchange: tagged u64 {tag32 | 2x bf16 delta}, DUAL-PUBLISHED:
//   local channel (sc0 asm -> stays in own XCD L2; fast iff group-mates share the
//   XCD, which the expected round-robin p%8 placement gives) and the R7-proven
//   LLC channel (relaxed agent atomics). Consumers poll local NLOC rounds with
//   per-word acceptance, then fall back to LLC — correct under ANY placement.
__global__ __launch_bounds__(256, 1) void scan_kernel(
    const ushort* __restrict__ texp_frag,
    const float* __restrict__ emitg,
    const float* __restrict__ start_v,
    u64* __restrict__ abuf,            // LLC channel [8 group][2 parity][2 rb][512]
    u64* __restrict__ labuf,           // local channel, same layout (no init needed)
    float* __restrict__ out)
{
  __shared__ ushort Atile[2 * 1024];   // rows = 2 batches, 1024 cols bf16
  __shared__ ushort zeros16[32];
  __shared__ float  redw[4][2];
  int tid = threadIdx.x, lane = tid & 63, wave = tid >> 6;
  int r16 = lane & 15, quad = lane >> 4;
  int p = blockIdx.x, g = p & 7, pg = p >> 3;
  u64* gx = abuf + g * 2048;
  u64* lx = labuf + g * 2048;
  int b0 = 2 * g, b1 = 2 * g + 1;
  int n0 = pg * 128 + wave * 32;       // wave's first col (2 tiles: n0, n0+16)
  const short8* tf0 = (const short8*)texp_frag + (size_t)(pg * 8 + wave * 2) * 2048;
  const short8* tf1 = tf0 + 2048;

  if (tid < 32) zeros16[tid] = 0;
  __syncthreads();

  float Bsum0 = 0.f, Bsum1 = 0.f;

  // one-step-ahead emission prefetch (for t=1)
  float e00 = 0.f, e01 = 0.f, e10 = 0.f, e11 = 0.f;
  if (quad == 0) {
    e00 = emitg[(size_t)(16 + b0) * 1024 + n0 + r16];
    e10 = emitg[(size_t)(16 + b1) * 1024 + n0 + r16];
    e01 = emitg[(size_t)(16 + b0) * 1024 + n0 + 16 + r16];
    e11 = emitg[(size_t)(16 + b1) * 1024 + n0 + 16 + r16];
  }

  for (int t = 1; t < 256; ++t) {
    float va[4][2];   // word i: rb = i>>1, c2 = (i&1)*256 + tid -> cols 2c2, 2c2+1
    float mA, mB;
    if (t == 1) {
      // delta0 computed locally (identical in all blocks): start + emit[t=0]
      mA = start_v[0] + emitg[(size_t)b0 * 1024];
      mB = start_v[0] + emitg[(size_t)b1 * 1024];
#pragma unroll
      for (int i = 0; i < 4; ++i) {
        int rb = i >> 1, c2 = (i & 1) * 256 + tid;
        const float* eb = emitg + (size_t)(rb ? b1 : b0) * 1024;
        va[i][0] = start_v[2 * c2]     + eb[2 * c2];
        va[i][1] = start_v[2 * c2 + 1] + eb[2 * c2 + 1];
      }
    } else {
      u32 want = (u32)(t - 1);
      const u64* lb = lx + ((t - 1) & 1) * 1024;
      const u64* gb = gx + ((t - 1) & 1) * 1024;
      u64 d[4], nw0 = 0, nw1 = 0;
      u32 pend = 0x3Fu;
      for (int round = 0; pend; ++round) {
        u64 x[6];
        if (round < NLOC) {
          // optimistic local-channel round (XCD L2 latency)
          poll6_sc0(lb + tid, lb + 256 + tid, lb + 512 + tid, lb + 768 + tid,
                    lb, lb + 512, x[0], x[1], x[2], x[3], x[4], x[5]);
        } else {
          if (round > NLOC) __builtin_amdgcn_s_sleep(1);
          if (pend & 1u)  x[0] = __hip_atomic_load(gb + tid,       __ATOMIC_RELAXED, __HIP_MEMORY_SCOPE_AGENT);
          if (pend & 2u)  x[1] = __hip_atomic_load(gb + 256 + tid, __ATOMIC_RELAXED, __HIP_MEMORY_SCOPE_AGENT);
          if (pend & 4u)  x[2] = __hip_atomic_load(gb + 512 + tid, __ATOMIC_RELAXED, __HIP_MEMORY_SCOPE_AGENT);
          if (pend & 8u)  x[3] = __hip_atomic_load(gb + 768 + tid, __ATOMIC_RELAXED, __HIP_MEMORY_SCOPE_AGENT);
          if (pend & 16u) x[4] = __hip_atomic_load(gb,             __ATOMIC_RELAXED, __HIP_MEMORY_SCOPE_AGENT);
          if (pend & 32u) x[5] = __hip_atomic_load(gb + 512,       __ATOMIC_RELAXED, __HIP_MEMORY_SCOPE_AGENT);
        }
#pragma unroll
        for (int i = 0; i < 4; ++i)
          if ((pend & (1u << i)) && (u32)(x[i] >> 32) == want) { d[i] = x[i]; pend &= ~(1u << i); }
        if ((pend & 16u) && (u32)(x[4] >> 32) == want) { nw0 = x[4]; pend &= ~16u; }
        if ((pend & 32u) && (u32)(x[5] >> 32) == want) { nw1 = x[5]; pend &= ~32u; }
      }
      mA = bflo2f((u32)nw0); mB = bflo2f((u32)nw1);
#pragma unroll
      for (int i = 0; i < 4; ++i) {
        u32 lo = (u32)d[i];
        va[i][0] = bflo2f(lo); va[i][1] = bfhi2f(lo);
      }
    }
    Bsum0 += mA; Bsum1 += mB;

    __syncthreads();   // all waves done reading Atile of previous step
    // exp + pack into Atile rows 0/1
#pragma unroll
    for (int i = 0; i < 4; ++i) {
      int rb = i >> 1, c2 = (i & 1) * 256 + tid;
      float m = rb ? mB : mA;
      u32 w = (u32)f2bf(__expf(va[i][0] - m)) |
              ((u32)f2bf(__expf(va[i][1] - m)) << 16);
      *(u32*)(Atile + rb * 1024 + c2 * 2) = w;
    }
    __syncthreads();   // Atile ready

    // emission prefetch for step t+1 (hidden under MFMA + next poll)
    float ne00 = 0.f, ne01 = 0.f, ne10 = 0.f, ne11 = 0.f;
    if (t < 255 && quad == 0) {
      ne00 = emitg[(size_t)((t + 1) * 16 + b0) * 1024 + n0 + r16];
      ne10 = emitg[(size_t)((t + 1) * 16 + b1) * 1024 + n0 + r16];
      ne01 = emitg[(size_t)((t + 1) * 16 + b0) * 1024 + n0 + 16 + r16];
      ne11 = emitg[(size_t)((t + 1) * 16 + b1) * 1024 + n0 + 16 + r16];
    }

    // K-loop: wave computes its 2 col-tiles over full K=1024
    f32x4 acc0 = {0.f, 0.f, 0.f, 0.f}, acc1 = {0.f, 0.f, 0.f, 0.f};
#pragma unroll 8
    for (int k = 0; k < 32; ++k) {
      const ushort* ap = (r16 < 2) ? (Atile + r16 * 1024 + k * 32 + quad * 8)
                                   : (zeros16 + quad * 8);
      short8 a = *(const short8*)ap;
      acc0 = __builtin_amdgcn_mfma_f32_16x16x32_bf16(a, tf0[k * 64 + lane], acc0, 0, 0, 0);
      acc1 = __builtin_amdgcn_mfma_f32_16x16x32_bf16(a, tf1[k * 64 + lane], acc1, 0, 0, 0);
    }

    // epilogue: quad0 lanes hold batch0 (reg0) and batch1 (reg1) for col n0(+16)+r16
    float d00 = __logf(acc0[0]) + e00, d10 = __logf(acc0[1]) + e10;
    float d01 = __logf(acc1[0]) + e01, d11 = __logf(acc1[1]) + e11;
    float p00 = __shfl_xor(d00, 1), p10 = __shfl_xor(d10, 1);
    float p01 = __shfl_xor(d01, 1), p11 = __shfl_xor(d11, 1);
    if (quad == 0 && !(r16 & 1)) {
      u64 tag = ((u64)(u32)t) << 32;
      int par = (t & 1) * 1024;
      u64* ob = gx + par;
      u64* lob = lx + par;
      int c2a = (n0 + r16) >> 1;
      int c2b = (n0 + 16 + r16) >> 1;
      u64 w0 = tag | (u64)((u32)f2bf(d00) | ((u32)f2bf(p00) << 16));
      u64 w1 = tag | (u64)((u32)f2bf(d01) | ((u32)f2bf(p01) << 16));
      u64 w2 = tag | (u64)((u32)f2bf(d10) | ((u32)f2bf(p10) << 16));
      u64 w3 = tag | (u64)((u32)f2bf(d11) | ((u32)f2bf(p11) << 16));
      // local channel first (same-XCD consumers see it at L2 latency)
      store8_sc0(lob + c2a, w0);
      store8_sc0(lob + c2b, w1);
      store8_sc0(lob + 512 + c2a, w2);
      store8_sc0(lob + 512 + c2b, w3);
      __hip_atomic_store(ob + c2a,       w0, __ATOMIC_RELAXED, __HIP_MEMORY_SCOPE_AGENT);
      __hip_atomic_store(ob + c2b,       w1, __ATOMIC_RELAXED, __HIP_MEMORY_SCOPE_AGENT);
      __hip_atomic_store(ob + 512 + c2a, w2, __ATOMIC_RELAXED, __HIP_MEMORY_SCOPE_AGENT);
      __hip_atomic_store(ob + 512 + c2b, w3, __ATOMIC_RELAXED, __HIP_MEMORY_SCOPE_AGENT);
    }
    e00 = ne00; e01 = ne01; e10 = ne10; e11 = ne11;
  }

  // ---- group leader (pg==0): reduce final delta + Bsum -> atomicAdd(out) ----
  if (pg == 0) {
    const u64* buf = gx + 1024;   // LLC channel, parity of t=255
    u64 d[4];
    u32 pend = 0xFu; bool first = true;
    while (pend) {
      if (!first) __builtin_amdgcn_s_sleep(1);
      first = false;
      u64 x[4];
      if (pend & 1u) x[0] = __hip_atomic_load(buf + tid,       __ATOMIC_RELAXED, __HIP_MEMORY_SCOPE_AGENT);
      if (pend & 2u) x[1] = __hip_atomic_load(buf + 256 + tid, __ATOMIC_RELAXED, __HIP_MEMORY_SCOPE_AGENT);
      if (pend & 4u) x[2] = __hip_atomic_load(buf + 512 + tid, __ATOMIC_RELAXED, __HIP_MEMORY_SCOPE_AGENT);
      if (pend & 8u) x[3] = __hip_atomic_load(buf + 768 + tid, __ATOMIC_RELAXED, __HIP_MEMORY_SCOPE_AGENT);
#pragma unroll
      for (int i = 0; i < 4; ++i)
        if ((pend & (1u << i)) && (u32)(x[i] >> 32) == 255u) { d[i] = x[i]; pend &= ~(1u << i); }
    }
    float lv[4][2];
#pragma unroll
    for (int i = 0; i < 4; ++i) {
      u32 lo = (u32)d[i];
      lv[i][0] = bflo2f(lo); lv[i][1] = bfhi2f(lo);
    }
    float M0 = fmaxf(fmaxf(lv[0][0], lv[0][1]), fmaxf(lv[1][0], lv[1][1]));
    float M1 = fmaxf(fmaxf(lv[2][0], lv[2][1]), fmaxf(lv[3][0], lv[3][1]));
    for (int m = 1; m < 64; m <<= 1) {
      M0 = fmaxf(M0, __shfl_xor(M0, m));
      M1 = fmaxf(M1, __shfl_xor(M1, m));
    }
    if (lane == 0) { redw[wave][0] = M0; redw[wave][1] = M1; }
    __syncthreads();
    M0 = fmaxf(fmaxf(redw[0][0], redw[1][0]), fmaxf(redw[2][0], redw[3][0]));
    M1 = fmaxf(fmaxf(redw[0][1], redw[1][1]), fmaxf(redw[2][1], redw[3][1]));
    __syncthreads();
    float S0 = __expf(lv[0][0] - M0) + __expf(lv[0][1] - M0) +
               __expf(lv[1][0] - M0) + __expf(lv[1][1] - M0);
    float S1 = __expf(lv[2][0] - M1) + __expf(lv[2][1] - M1) +
               __expf(lv[3][0] - M1) + __expf(lv[3][1] - M1);
    for (int m = 1; m < 64; m <<= 1) {
      S0 += __shfl_xor(S0, m);
      S1 += __shfl_xor(S1, m);
    }
    if (lane == 0) { redw[wave][0] = S0; redw[wave][1] = S1; }
    __syncthreads();
    if (tid == 0) {
      float s0 = redw[0][0] + redw[1][0] + redw[2][0] + redw[3][0];
      float s1 = redw[0][1] + redw[1][1] + redw[2][1] + redw[3][1];
      float total = (Bsum0 + M0 + __logf(s0)) + (Bsum1 + M1 + __logf(s1));
      atomicAdd(out, total);
    }
  }
}

extern "C" void kernel_launch(void* const* d_in, const int* in_sizes, int n_in,
                              void* d_out, int out_size, void* d_ws, size_t ws_size,
                              hipStream_t stream)
{
  (void)in_sizes; (void)n_in; (void)out_size; (void)ws_size;
  const float* start_emb = (const float*)d_in[0];
  const float* state_emb = (const float*)d_in[1];
  const float* pre_emb   = (const float*)d_in[2];
  const float* s_W1 = (const float*)d_in[3];  const float* s_b1 = (const float*)d_in[4];
  const float* s_W2 = (const float*)d_in[5];  const float* s_b2 = (const float*)d_in[6];
  const float* s_g  = (const float*)d_in[7];  const float* s_be = (const float*)d_in[8];
  const float* s_Wo = (const float*)d_in[9];  const float* s_bo = (const float*)d_in[10];
  const float* t_W1 = (const float*)d_in[11]; const float* t_b1 = (const float*)d_in[12];
  const float* t_W2 = (const float*)d_in[13]; const float* t_b2 = (const float*)d_in[14];
  const float* t_g  = (const float*)d_in[15]; const float* t_be = (const float*)d_in[16];
  const float* t_Wo = (const float*)d_in[17]; const float* t_bo = (const float*)d_in[18];
  const float* e_W1 = (const float*)d_in[19]; const float* e_b1 = (const float*)d_in[20];
  const float* e_W2 = (const float*)d_in[21]; const float* e_b2 = (const float*)d_in[22];
  const float* e_g  = (const float*)d_in[23]; const float* e_be = (const float*)d_in[24];
  const float* e_Wo = (const float*)d_in[25]; const float* e_bo = (const float*)d_in[26];
  const int*   text = (const int*)d_in[27];
  float* out = (float*)d_out;

  char* ws = (char*)d_ws;
  size_t off = 0;
  auto alloc = [&](size_t bytes) -> char* {
    char* p = ws + off;
    off = (off + bytes + 255) & ~(size_t)255;
    return p;
  };
  float* esum       = (float*)alloc(1024 * 4);     // @0 (memset)
  u64*   abuf       = (u64*)alloc(8 * 2048 * 8);   // LLC exchange channel
  u64*   labuf      = (u64*)alloc(8 * 2048 * 8);   // local (XCD-L2) exchange channel
  float* start_v    = (float*)alloc(1024 * 4);
  float* h_s        = (float*)alloc(1024 * 256 * 4);
  ushort* h_t_bf    = (ushort*)alloc(1024 * 256 * 2);
  ushort* h_e_bf    = (ushort*)alloc(1024 * 256 * 2);
  ushort* tWo_bf    = (ushort*)alloc(1024 * 256 * 2);
  ushort* eWo_bf    = (ushort*)alloc(10000 * 256 * 2);
  float* tlogits    = (float*)alloc(1024 * 1024 * 4);
  ushort* texp_frag = (ushort*)alloc(1024 * 1024 * 2);
  float* emitg      = (float*)alloc(4096 * 1024 * 4);

  hipMemsetAsync(ws, 0, 4096, stream);   // esum
  hipMemsetAsync(d_out, 0, 4, stream);   // leaders atomicAdd into out

  cast2_kernel<<<768, 256, 0, stream>>>(t_Wo, tWo_bf, 1024 * 256, e_Wo, eWo_bf, 10000 * 256);

  mlp3_kernel<<<dim3(64, 3), 256, 0, stream>>>(
      start_emb, s_W1, s_b1, s_W2, s_b2, s_g, s_be, h_s, nullptr,
      state_emb, t_W1, t_b1, t_W2, t_b2, t_g, t_be, nullptr, h_t_bf,
      pre_emb,  e_W1, e_b1, e_W2, e_b2, e_g, e_be, nullptr, h_e_bf);

  shead_kernel<<<1, 1024, 0, stream>>>(h_s, s_Wo, s_bo, start_v);

  gemm_kernel<<<dim3(16, 32),  256, 0, stream>>>(h_t_bf, tWo_bf, 0, 1024,  t_bo, tlogits, nullptr, nullptr);
  trans_kernel<<<1024, 256, 0, stream>>>(tlogits, texp_frag);
  gemm_kernel<<<dim3(16, 313), 256, 0, stream>>>(h_e_bf, eWo_bf, 1, 10000, e_bo, nullptr, esum, nullptr);
  gemm_kernel<<<dim3(16, 128), 256, 0, stream>>>(h_e_bf, eWo_bf, 2, 4096,  e_bo, emitg, esum, text);

  scan_kernel<<<GBLK, 256, 0, stream>>>(texp_frag, emitg, start_v, abuf, labuf, out);
}